// Round 2
// baseline (393.501 us; speedup 1.0000x reference)
//
#include <hip/hip_runtime.h>
#include <hip/hip_bf16.h>

typedef __bf16 bf16x8 __attribute__((ext_vector_type(8)));
typedef float  f32x4  __attribute__((ext_vector_type(4)));

#define K_TOTAL (64*64*64)          // 262144
#define B_DIM   32
#define A_DIM   256
#define G_SPLIT 256                 // number of K-chunks (= grid of kernel 2)
#define K_CHUNK (K_TOTAL / G_SPLIT) // 1024

// ---------------------------------------------------------------------------
// Kernel 1: x123[b, n*4096 + m*64 + o] = x1[b,n]*x2[b,m]*x3[b,o]  (bf16)
// One thread per 8 consecutive o. 32*64*64*8 = 1,048,576 threads.
// ---------------------------------------------------------------------------
__global__ __launch_bounds__(256) void build_x123(
    const float* __restrict__ x1, const float* __restrict__ x2,
    const float* __restrict__ x3, __bf16* __restrict__ X)
{
    int t  = blockIdx.x * blockDim.x + threadIdx.x;  // 0 .. 2^20-1
    int o8 = t & 7;
    int m  = (t >> 3) & 63;
    int n  = (t >> 9) & 63;
    int b  = t >> 15;

    float p12 = x1[b * 64 + n] * x2[b * 64 + m];
    const f32x4* x3v = reinterpret_cast<const f32x4*>(x3 + b * 64 + o8 * 8);
    f32x4 c0 = x3v[0];
    f32x4 c1 = x3v[1];

    bf16x8 outv;
#pragma unroll
    for (int i = 0; i < 4; ++i) {
        outv[i]     = (__bf16)(p12 * c0[i]);
        outv[i + 4] = (__bf16)(p12 * c1[i]);
    }
    *reinterpret_cast<bf16x8*>(X + (size_t)t * 8) = outv;
}

// ---------------------------------------------------------------------------
// Kernel 2: split-K GEMM. partials[g][b][a] = sum_{k in chunk g} X[b,k]*W[a,k]
// Block g: K-chunk of 1024. 1024 threads = 16 waves; wave w owns a-tile
// [16w, 16w+16), both M-tiles (b 0-15 and 16-31).
// mfma_f32_16x16x32_bf16: A row = lane&15, B col = lane&15,
//                         k = (lane>>4)*8 + j;  D row=(lane>>4)*4+r, col=lane&15.
// ---------------------------------------------------------------------------
__global__ __launch_bounds__(1024, 4) void gemm_splitk(
    const __bf16* __restrict__ X,    // [32][K_TOTAL] bf16
    const float*  __restrict__ W,    // [256][K_TOTAL] fp32
    float* __restrict__ partials)    // [G_SPLIT][32][256] fp32
{
    const int g     = blockIdx.x;
    const int kbase = g * K_CHUNK;
    const int wave  = threadIdx.x >> 6;   // 0..15
    const int lane  = threadIdx.x & 63;
    const int l15   = lane & 15;
    const int lg    = lane >> 4;          // 0..3
    const int a0    = wave * 16;

    f32x4 acc0 = {0.f, 0.f, 0.f, 0.f};   // rows b = 0..15
    f32x4 acc1 = {0.f, 0.f, 0.f, 0.f};   // rows b = 16..31

    const __bf16* Arow0 = X + (size_t)l15        * K_TOTAL + kbase + lg * 8;
    const __bf16* Arow1 = X + (size_t)(l15 + 16) * K_TOTAL + kbase + lg * 8;
    const float*  Brow  = W + (size_t)(a0 + l15) * K_TOTAL + kbase + lg * 8;

#pragma unroll 4
    for (int ks = 0; ks < K_CHUNK; ks += 32) {
        bf16x8 afrag0 = *reinterpret_cast<const bf16x8*>(Arow0 + ks);
        bf16x8 afrag1 = *reinterpret_cast<const bf16x8*>(Arow1 + ks);
        f32x4 w0 = *reinterpret_cast<const f32x4*>(Brow + ks);
        f32x4 w1 = *reinterpret_cast<const f32x4*>(Brow + ks + 4);

        bf16x8 bfrag;
#pragma unroll
        for (int i = 0; i < 4; ++i) {
            bfrag[i]     = (__bf16)w0[i];
            bfrag[i + 4] = (__bf16)w1[i];
        }
        acc0 = __builtin_amdgcn_mfma_f32_16x16x32_bf16(afrag0, bfrag, acc0, 0, 0, 0);
        acc1 = __builtin_amdgcn_mfma_f32_16x16x32_bf16(afrag1, bfrag, acc1, 0, 0, 0);
    }

    float* p = partials + (size_t)g * (B_DIM * A_DIM);
#pragma unroll
    for (int r = 0; r < 4; ++r) {
        p[(lg * 4 + r) * A_DIM      + a0 + l15] = acc0[r];
        p[(16 + lg * 4 + r) * A_DIM + a0 + l15] = acc1[r];
    }
}

// ---------------------------------------------------------------------------
// Kernel 3: out[b][a] = bias[a] + sum_g partials[g][b][a]
// 256 blocks: block = (b, a-chunk of 32). 256 threads: (a within chunk) x
// (8 g-slices of 32), LDS tree over slices.
// ---------------------------------------------------------------------------
__global__ __launch_bounds__(256) void reduce_partials(
    const float* __restrict__ partials, const float* __restrict__ bias,
    float* __restrict__ out)
{
    int blk = blockIdx.x;        // 0..255
    int b   = blk >> 3;          // 0..31
    int ac  = blk & 7;           // a-chunk
    int t   = threadIdx.x;
    int a   = ac * 32 + (t & 31);
    int gs  = t >> 5;            // 0..7

    float s = 0.f;
#pragma unroll 4
    for (int i = 0; i < 32; ++i) {
        int g = gs * 32 + i;
        s += partials[((size_t)g * B_DIM + b) * A_DIM + a];
    }

    __shared__ float red[256];
    red[t] = s;
    __syncthreads();
    if (t < 32) {
        float tot = red[t];
#pragma unroll
        for (int j = 1; j < 8; ++j) tot += red[t + 32 * j];
        out[b * A_DIM + a] = tot + bias[a];
    }
}

extern "C" void kernel_launch(void* const* d_in, const int* in_sizes, int n_in,
                              void* d_out, int out_size, void* d_ws, size_t ws_size,
                              hipStream_t stream) {
    const float* x1   = (const float*)d_in[0];
    const float* x2   = (const float*)d_in[1];
    const float* x3   = (const float*)d_in[2];
    const float* W    = (const float*)d_in[3];
    const float* bias = (const float*)d_in[4];
    float* out = (float*)d_out;

    __bf16* X       = (__bf16*)d_ws;
    float* partials = (float*)((char*)d_ws + (size_t)B_DIM * K_TOTAL * 2);

    hipLaunchKernelGGL(build_x123, dim3((B_DIM * K_TOTAL / 8) / 256), dim3(256),
                       0, stream, x1, x2, x3, X);
    hipLaunchKernelGGL(gemm_splitk, dim3(G_SPLIT), dim3(1024),
                       0, stream, X, W, partials);
    hipLaunchKernelGGL(reduce_partials, dim3(256), dim3(256),
                       0, stream, partials, bias, out);
}

// Round 4
// 393.325 us; speedup vs baseline: 1.0004x; 1.0004x over previous
//
#include <hip/hip_runtime.h>
#include <hip/hip_bf16.h>

typedef __bf16 bf16x8 __attribute__((ext_vector_type(8)));
typedef __bf16 bf16x4 __attribute__((ext_vector_type(4)));
typedef float  f32x4  __attribute__((ext_vector_type(4)));

#define K_TOTAL (64*64*64)   // 262144
#define B_DIM   32
#define A_DIM   256
#define KC      512          // k elements per gemm block
#define NKC     (K_TOTAL/KC) // 512 k-chunks
#define ATILE   64           // a rows per gemm block
#define NAT     (A_DIM/ATILE)// 4
#define WSTRIDE 520          // LDS row stride in bf16 (512 + 8 pad)

// ---------------------------------------------------------------------------
// Kernel 1: X'[k/32][b][k%32] = x1[b,n]*x2[b,m]*x3[b,o], k = n*4096+m*64+o.
// MFMA-native tile order: a wave's A-fragment load is one contiguous 1 KiB.
// Thread t -> b = t>>15, k8 = t&32767 (8 consecutive o / k).
// ---------------------------------------------------------------------------
__global__ __launch_bounds__(256) void build_xp(
    const float* __restrict__ x1, const float* __restrict__ x2,
    const float* __restrict__ x3, __bf16* __restrict__ Xp)
{
    int t  = blockIdx.x * blockDim.x + threadIdx.x;  // 0 .. 2^20-1
    int k8 = t & 32767;
    int b  = t >> 15;
    int o8 = k8 & 7;
    int m  = (k8 >> 3) & 63;
    int n  = k8 >> 9;

    float p12 = x1[b * 64 + n] * x2[b * 64 + m];
    f32x4 c0 = *reinterpret_cast<const f32x4*>(x3 + b * 64 + o8 * 8);
    f32x4 c1 = *reinterpret_cast<const f32x4*>(x3 + b * 64 + o8 * 8 + 4);

    bf16x8 v;
#pragma unroll
    for (int i = 0; i < 4; ++i) {
        v[i]     = (__bf16)(p12 * c0[i]);
        v[i + 4] = (__bf16)(p12 * c1[i]);
    }
    int k = k8 * 8;
    size_t off = (size_t)(k >> 5) * 1024 + b * 32 + (k & 31);
    *reinterpret_cast<bf16x8*>(Xp + off) = v;
}

// ---------------------------------------------------------------------------
// Kernel 2: staged split-K GEMM.
// Block (at, kc): a-rows [at*64, +64), k in [kc*512, +512).
// Stage W fp32 -> bf16 LDS with contiguous 1 KiB bursts (W streamed exactly
// once, full-line coalesced, no pow-2 stride inside an instruction).
// 4 waves; wave w owns a-rows [w*16, +16), computes [32 b x 16 a] partial.
// A-fragments come from packed X' (contiguous 1 KiB per load instruction).
// ---------------------------------------------------------------------------
__global__ __launch_bounds__(256, 2) void gemm_staged(
    const __bf16* __restrict__ Xp,   // [K_TOTAL/32][32][32] bf16
    const float*  __restrict__ W,    // [256][K_TOTAL] fp32
    float* __restrict__ partials)    // [NKC][32][256] fp32
{
    __shared__ __bf16 w_lds[ATILE * WSTRIDE];

    const int bid  = blockIdx.x;     // 0..2047
    const int at   = bid & (NAT - 1);
    const int kc   = bid >> 2;       // 0..511
    const int wv   = threadIdx.x >> 6;
    const int lane = threadIdx.x & 63;

    // ---- stage: wave wv loads rows [wv*16, +16), 2 KiB per row ----
    const float* wbase = W + (size_t)(at * ATILE + wv * 16) * K_TOTAL + kc * KC;
#pragma unroll 4
    for (int i = 0; i < 16; ++i) {
        const float* wr = wbase + (size_t)i * K_TOTAL;
        f32x4 lo = *reinterpret_cast<const f32x4*>(wr + lane * 4);
        f32x4 hi = *reinterpret_cast<const f32x4*>(wr + 256 + lane * 4);
        bf16x4 blo, bhi;
#pragma unroll
        for (int j = 0; j < 4; ++j) {
            blo[j] = (__bf16)lo[j];
            bhi[j] = (__bf16)hi[j];
        }
        __bf16* dst = w_lds + (wv * 16 + i) * WSTRIDE;
        *reinterpret_cast<bf16x4*>(dst + lane * 4)       = blo;
        *reinterpret_cast<bf16x4*>(dst + 256 + lane * 4) = bhi;
    }
    __syncthreads();

    // ---- compute ----
    const int l15 = lane & 15;
    const int lg  = lane >> 4;

    f32x4 acc0 = {0.f, 0.f, 0.f, 0.f};   // b = 0..15
    f32x4 acc1 = {0.f, 0.f, 0.f, 0.f};   // b = 16..31

    const __bf16* arow = Xp + (size_t)(kc * (KC / 32)) * 1024 + l15 * 32 + lg * 8;
    const __bf16* brow = w_lds + (wv * 16 + l15) * WSTRIDE + lg * 8;

#pragma unroll 4
    for (int kk = 0; kk < KC / 32; ++kk) {   // 16 k-steps of 32
        bf16x8 a0 = *reinterpret_cast<const bf16x8*>(arow + kk * 1024);
        bf16x8 a1 = *reinterpret_cast<const bf16x8*>(arow + kk * 1024 + 512);
        bf16x8 bb = *reinterpret_cast<const bf16x8*>(brow + kk * 32);
        acc0 = __builtin_amdgcn_mfma_f32_16x16x32_bf16(a0, bb, acc0, 0, 0, 0);
        acc1 = __builtin_amdgcn_mfma_f32_16x16x32_bf16(a1, bb, acc1, 0, 0, 0);
    }

    // ---- write partials[kc][b][a] ----
    float* p = partials + (size_t)kc * (B_DIM * A_DIM)
                        + (at * ATILE + wv * 16 + l15);
#pragma unroll
    for (int r = 0; r < 4; ++r) {
        p[(lg * 4 + r) * A_DIM]        = acc0[r];
        p[(16 + lg * 4 + r) * A_DIM]   = acc1[r];
    }
}

// ---------------------------------------------------------------------------
// Kernel 3: out[b][a] = bias[a] + sum_kc partials[kc][b][a]
// 256 blocks = (b, a-chunk of 32); 256 threads = 32 a x 8 kc-slices.
// ---------------------------------------------------------------------------
__global__ __launch_bounds__(256) void reduce_partials(
    const float* __restrict__ partials, const float* __restrict__ bias,
    float* __restrict__ out)
{
    int blk = blockIdx.x;        // 0..255
    int b   = blk >> 3;
    int ac  = blk & 7;
    int t   = threadIdx.x;
    int a   = ac * 32 + (t & 31);
    int gs  = t >> 5;            // 0..7

    float s = 0.f;
#pragma unroll 4
    for (int i = 0; i < NKC / 8; ++i) {   // 64 k-chunks per slice
        int kc = gs * (NKC / 8) + i;
        s += partials[((size_t)kc * B_DIM + b) * A_DIM + a];
    }

    __shared__ float red[256];
    red[t] = s;
    __syncthreads();
    if (t < 32) {
        float tot = red[t];
#pragma unroll
        for (int j = 1; j < 8; ++j) tot += red[t + 32 * j];
        out[b * A_DIM + a] = tot + bias[a];
    }
}

extern "C" void kernel_launch(void* const* d_in, const int* in_sizes, int n_in,
                              void* d_out, int out_size, void* d_ws, size_t ws_size,
                              hipStream_t stream) {
    const float* x1   = (const float*)d_in[0];
    const float* x2   = (const float*)d_in[1];
    const float* x3   = (const float*)d_in[2];
    const float* W    = (const float*)d_in[3];
    const float* bias = (const float*)d_in[4];
    float* out = (float*)d_out;

    __bf16* Xp      = (__bf16*)d_ws;                                   // 16 MB
    float* partials = (float*)((char*)d_ws + (size_t)B_DIM * K_TOTAL * 2); // 16 MB

    hipLaunchKernelGGL(build_xp, dim3((B_DIM * K_TOTAL / 8) / 256), dim3(256),
                       0, stream, x1, x2, x3, Xp);
    hipLaunchKernelGGL(gemm_staged, dim3(NAT * NKC), dim3(256),
                       0, stream, Xp, W, partials);
    hipLaunchKernelGGL(reduce_partials, dim3(256), dim3(256),
                       0, stream, partials, bias, out);
}